// Round 1
// baseline (559.048 us; speedup 1.0000x reference)
//
#include <hip/hip_runtime.h>

// positional_spiking_attention: T=4, B=4, L=1024, D=512, H=8(irrelevant), WINDOW=8
// Pipeline: first_lif -> {q,k,v} = lif(bn(linear(xs))) -> kv=k*v ->
//           banded conv along L (window 8, weights pos_bias[i,i-w]) * q ->
//           attn_lif -> bn(linear(.)) -> out
//
// Workspace layout (fp32, 4 x 33554432 B = 128 MB):
//   ws + 0   : xs   (first_lif spikes)      [T,B,L,D]
//   ws + 32M : yq   -> q spikes (in-place)
//   ws + 64M : yk   -> kv = k*v (in-place)
//   ws + 96M : yv   -> attn_lif spikes s (overwritten by k_attn_lif)

#define T_ 4
#define B_ 4
#define L_ 1024
#define D_ 512
#define M_ROWS (T_*B_*L_)            // 16384 GEMM rows
#define STRIDE4 (B_*L_*D_/4)         // 524288 float4 per time step
#define BUF_BYTES (size_t)(T_*B_*L_*D_*4)  // 33554432

#define INV_STD 0.9999950000374997f  // 1/sqrt(1+1e-5), rounded to f32

static __device__ __forceinline__ float spike_of(float m) {
  return m > 0.5f ? 1.0f : 0.0f;
}

// ---------------- kernel 1: first LIF ----------------
__global__ __launch_bounds__(256) void k_lif_first(const float* __restrict__ x,
                                                   float* __restrict__ xs) {
  int idx = blockIdx.x * 256 + threadIdx.x;
  if (idx >= STRIDE4) return;
  const float4* x4 = (const float4*)x;
  float4* o4 = (float4*)xs;
  float m[4], s[4];
  float4 v = x4[idx];
  m[0] = v.x; m[1] = v.y; m[2] = v.z; m[3] = v.w;
#pragma unroll
  for (int c = 0; c < 4; ++c) s[c] = spike_of(m[c]);
  o4[idx] = make_float4(s[0], s[1], s[2], s[3]);
#pragma unroll
  for (int t = 1; t < T_; ++t) {
    v = x4[idx + t * STRIDE4];
    float xv[4] = {v.x, v.y, v.z, v.w};
#pragma unroll
    for (int c = 0; c < 4; ++c) {
      m[c] = m[c] * 0.25f * (1.0f - s[c]) + xv[c];
      s[c] = spike_of(m[c]);
    }
    o4[idx + t * STRIDE4] = make_float4(s[0], s[1], s[2], s[3]);
  }
}

// ---------------- kernel 2: SGEMM + BN epilogue ----------------
// Y[r,e] = (sum_d A[r,d]*W[e,d] + bias[e]) * (INV_STD*gamma[e]) + beta[e]
// A: [M,512] row-major; W: [512,512] row-major [e,d].
// 128x128 tile, BK=8, 256 threads, 8x8 accum per thread.
__global__ __launch_bounds__(256) void k_gemm_bn(const float* __restrict__ A,
                                                 const float* __restrict__ W,
                                                 const float* __restrict__ bias,
                                                 const float* __restrict__ gamma,
                                                 const float* __restrict__ beta,
                                                 float* __restrict__ Y) {
  __shared__ float As[8][128];
  __shared__ float Ws[8][128];
  const int tid = threadIdx.x;
  const int tx = tid & 15, ty = tid >> 4;
  const int row0 = blockIdx.y * 128, col0 = blockIdx.x * 128;
  const int lr = tid >> 1;          // 0..127
  const int lc = (tid & 1) * 4;     // 0 or 4
  const float* Ag = A + (size_t)(row0 + lr) * D_ + lc;
  const float* Wg = W + (size_t)(col0 + lr) * D_ + lc;

  float acc[8][8] = {};

  for (int k0 = 0; k0 < D_; k0 += 8) {
    float4 av = *(const float4*)(Ag + k0);
    float4 wv = *(const float4*)(Wg + k0);
    __syncthreads();
    As[lc + 0][lr] = av.x; As[lc + 1][lr] = av.y;
    As[lc + 2][lr] = av.z; As[lc + 3][lr] = av.w;
    Ws[lc + 0][lr] = wv.x; Ws[lc + 1][lr] = wv.y;
    Ws[lc + 2][lr] = wv.z; Ws[lc + 3][lr] = wv.w;
    __syncthreads();
#pragma unroll
    for (int k = 0; k < 8; ++k) {
      float4 a0 = *(const float4*)&As[k][ty * 4];
      float4 a1 = *(const float4*)&As[k][64 + ty * 4];
      float4 b0 = *(const float4*)&Ws[k][tx * 4];
      float4 b1 = *(const float4*)&Ws[k][64 + tx * 4];
      float ar[8] = {a0.x, a0.y, a0.z, a0.w, a1.x, a1.y, a1.z, a1.w};
      float br[8] = {b0.x, b0.y, b0.z, b0.w, b1.x, b1.y, b1.z, b1.w};
#pragma unroll
      for (int i = 0; i < 8; ++i)
#pragma unroll
        for (int j = 0; j < 8; ++j) acc[i][j] += ar[i] * br[j];
    }
  }

#pragma unroll
  for (int jh = 0; jh < 2; ++jh) {
    const int cbase = col0 + jh * 64 + tx * 4;
    float4 bi = *(const float4*)(bias + cbase);
    float4 ga = *(const float4*)(gamma + cbase);
    float4 be = *(const float4*)(beta + cbase);
    float cb[4] = {bi.x, bi.y, bi.z, bi.w};
    float cs[4] = {INV_STD * ga.x, INV_STD * ga.y, INV_STD * ga.z, INV_STD * ga.w};
    float ct[4] = {be.x, be.y, be.z, be.w};
#pragma unroll
    for (int ih = 0; ih < 2; ++ih)
#pragma unroll
      for (int i = 0; i < 4; ++i) {
        const int r = row0 + ih * 64 + ty * 4 + i;
        float4 o;
        o.x = (acc[ih * 4 + i][jh * 4 + 0] + cb[0]) * cs[0] + ct[0];
        o.y = (acc[ih * 4 + i][jh * 4 + 1] + cb[1]) * cs[1] + ct[1];
        o.z = (acc[ih * 4 + i][jh * 4 + 2] + cb[2]) * cs[2] + ct[2];
        o.w = (acc[ih * 4 + i][jh * 4 + 3] + cb[3]) * cs[3] + ct[3];
        *(float4*)(Y + (size_t)r * D_ + cbase) = o;
      }
  }
}

// ---------------- kernel 3: LIF over q,k,v; q in-place; kv=k*v into yk ----------------
__global__ __launch_bounds__(256) void k_lif_qkv(float* __restrict__ yq,
                                                 float* __restrict__ yk,
                                                 float* __restrict__ yv) {
  int idx = blockIdx.x * 256 + threadIdx.x;
  if (idx >= STRIDE4) return;
  float4* q4 = (float4*)yq;
  float4* k4 = (float4*)yk;
  float4* v4 = (float4*)yv;

  // q: LIF, write spikes in place
  {
    float m[4], s[4];
    float4 y = q4[idx];
    m[0] = y.x; m[1] = y.y; m[2] = y.z; m[3] = y.w;
#pragma unroll
    for (int c = 0; c < 4; ++c) s[c] = spike_of(m[c]);
    q4[idx] = make_float4(s[0], s[1], s[2], s[3]);
#pragma unroll
    for (int t = 1; t < T_; ++t) {
      y = q4[idx + t * STRIDE4];
      float yv_[4] = {y.x, y.y, y.z, y.w};
#pragma unroll
      for (int c = 0; c < 4; ++c) {
        m[c] = m[c] * 0.25f * (1.0f - s[c]) + yv_[c];
        s[c] = spike_of(m[c]);
      }
      q4[idx + t * STRIDE4] = make_float4(s[0], s[1], s[2], s[3]);
    }
  }

  // k: LIF, keep spikes in registers
  float sk[T_][4];
  {
    float m[4];
    float4 y = k4[idx];
    m[0] = y.x; m[1] = y.y; m[2] = y.z; m[3] = y.w;
#pragma unroll
    for (int c = 0; c < 4; ++c) sk[0][c] = spike_of(m[c]);
#pragma unroll
    for (int t = 1; t < T_; ++t) {
      y = k4[idx + t * STRIDE4];
      float yv_[4] = {y.x, y.y, y.z, y.w};
#pragma unroll
      for (int c = 0; c < 4; ++c) {
        m[c] = m[c] * 0.25f * (1.0f - sk[t - 1][c]) + yv_[c];
        sk[t][c] = spike_of(m[c]);
      }
    }
  }

  // v: LIF, write kv = sk*sv into yk (k buffer no longer needed)
  {
    float m[4], s[4];
    float4 y = v4[idx];
    m[0] = y.x; m[1] = y.y; m[2] = y.z; m[3] = y.w;
#pragma unroll
    for (int c = 0; c < 4; ++c) s[c] = spike_of(m[c]);
    k4[idx] = make_float4(sk[0][0] * s[0], sk[0][1] * s[1],
                          sk[0][2] * s[2], sk[0][3] * s[3]);
#pragma unroll
    for (int t = 1; t < T_; ++t) {
      y = v4[idx + t * STRIDE4];
      float yv_[4] = {y.x, y.y, y.z, y.w};
#pragma unroll
      for (int c = 0; c < 4; ++c) {
        m[c] = m[c] * 0.25f * (1.0f - s[c]) + yv_[c];
        s[c] = spike_of(m[c]);
      }
      k4[idx + t * STRIDE4] = make_float4(sk[t][0] * s[0], sk[t][1] * s[1],
                                          sk[t][2] * s[2], sk[t][3] * s[3]);
    }
  }
}

// ---------------- kernel 4: banded positional mixing + attn_lif ----------------
// pre[t,b,i,d] = q[t,b,i,d] * sum_{w=0..min(7,i)} pb[i,i-w] * kv[t,b,i-w,d]
// then LIF over t; spikes written to sout.
__global__ __launch_bounds__(256) void k_attn_lif(const float* __restrict__ q,
                                                  const float* __restrict__ kv,
                                                  const float* __restrict__ pos_bias,
                                                  float* __restrict__ sout) {
  int idx = blockIdx.x * 256 + threadIdx.x;  // (b*L + i) * 128 + d4
  if (idx >= STRIDE4) return;
  const int d4 = idx & 127;
  const int bi = idx >> 7;     // b*L + i
  const int i = bi & (L_ - 1);
  const int wmax = i < 7 ? i : 7;

  float pbv[8];
  const float* pbrow = pos_bias + (size_t)i * L_ + i;
  for (int w = 0; w <= wmax; ++w) pbv[w] = pbrow[-w];

  const float4* q4 = (const float4*)q;
  const float4* kv4 = (const float4*)kv;
  float pre[T_][4];

#pragma unroll
  for (int t = 0; t < T_; ++t) {
    float sum[4] = {0.f, 0.f, 0.f, 0.f};
    const int tb = t * STRIDE4;
    for (int w = wmax; w >= 0; --w) {  // ascending j = i-w
      float4 kvv = kv4[tb + (bi - w) * 128 + d4];
      sum[0] += pbv[w] * kvv.x;
      sum[1] += pbv[w] * kvv.y;
      sum[2] += pbv[w] * kvv.z;
      sum[3] += pbv[w] * kvv.w;
    }
    float4 qv = q4[tb + bi * 128 + d4];
    pre[t][0] = qv.x * sum[0];
    pre[t][1] = qv.y * sum[1];
    pre[t][2] = qv.z * sum[2];
    pre[t][3] = qv.w * sum[3];
  }

  float4* s4 = (float4*)sout;
  float m[4], s[4];
#pragma unroll
  for (int c = 0; c < 4; ++c) { m[c] = pre[0][c]; s[c] = spike_of(m[c]); }
  s4[idx] = make_float4(s[0], s[1], s[2], s[3]);
#pragma unroll
  for (int t = 1; t < T_; ++t) {
#pragma unroll
    for (int c = 0; c < 4; ++c) {
      m[c] = m[c] * 0.25f * (1.0f - s[c]) + pre[t][c];
      s[c] = spike_of(m[c]);
    }
    s4[idx + t * STRIDE4] = make_float4(s[0], s[1], s[2], s[3]);
  }
}

extern "C" void kernel_launch(void* const* d_in, const int* in_sizes, int n_in,
                              void* d_out, int out_size, void* d_ws, size_t ws_size,
                              hipStream_t stream) {
  (void)in_sizes; (void)n_in; (void)out_size; (void)ws_size;
  const float* x        = (const float*)d_in[0];
  const float* pos_bias = (const float*)d_in[1];
  const float* q_w    = (const float*)d_in[2];
  const float* q_b    = (const float*)d_in[3];
  const float* q_g    = (const float*)d_in[4];
  const float* q_beta = (const float*)d_in[5];
  const float* k_w    = (const float*)d_in[6];
  const float* k_b    = (const float*)d_in[7];
  const float* k_g    = (const float*)d_in[8];
  const float* k_beta = (const float*)d_in[9];
  const float* v_w    = (const float*)d_in[10];
  const float* v_b    = (const float*)d_in[11];
  const float* v_g    = (const float*)d_in[12];
  const float* v_beta = (const float*)d_in[13];
  const float* last_w    = (const float*)d_in[14];
  const float* last_b    = (const float*)d_in[15];
  const float* last_g    = (const float*)d_in[16];
  const float* last_beta = (const float*)d_in[17];
  float* out = (float*)d_out;

  char* ws = (char*)d_ws;
  float* xs = (float*)(ws + 0 * BUF_BYTES);
  float* yq = (float*)(ws + 1 * BUF_BYTES);
  float* yk = (float*)(ws + 2 * BUF_BYTES);
  float* yv = (float*)(ws + 3 * BUF_BYTES);

  const int ew_blocks = STRIDE4 / 256;  // 2048
  dim3 ggrid(D_ / 128, M_ROWS / 128);   // (4, 128)

  k_lif_first<<<ew_blocks, 256, 0, stream>>>(x, xs);
  k_gemm_bn<<<ggrid, 256, 0, stream>>>(xs, q_w, q_b, q_g, q_beta, yq);
  k_gemm_bn<<<ggrid, 256, 0, stream>>>(xs, k_w, k_b, k_g, k_beta, yk);
  k_gemm_bn<<<ggrid, 256, 0, stream>>>(xs, v_w, v_b, v_g, v_beta, yv);
  k_lif_qkv<<<ew_blocks, 256, 0, stream>>>(yq, yk, yv);
  k_attn_lif<<<ew_blocks, 256, 0, stream>>>(yq, yk, pos_bias, yv);
  k_gemm_bn<<<ggrid, 256, 0, stream>>>(yv, last_w, last_b, last_g, last_beta, out);
}